// Round 6
// baseline (1805.821 us; speedup 1.0000x reference)
//
#include <hip/hip_runtime.h>
#include <hip/hip_bf16.h>
#include <math.h>

// ---------------------------------------------------------------------------
// Problem constants
// ---------------------------------------------------------------------------
#define NBATCH 1024
#define LIN    6000
#define HCATW  7640       // 20*375 + 20*7
#define HID    100

// conv-chain chunking: T=44 final(375-res) positions per block, 9 chunks
#define TCH   44
#define NCHK  9

#define ASZ 5824            // max(x-buf 3*734=2202, s1-out 32*182=5824)
#define BSZ 7320            // max(s0-out 20*366=7320, s2-out 64*90=5760)

// repacked-weight offsets (floats) inside wrep
#define W0OFF 0             // 4ocg*3ic*16  = 192
#define W1OFF 192           // 4*20*24      = 1920
#define W2OFF 2112          // 8*32*24      = 6144
#define W3OFF 8256          // 4*64*16      = 4096
#define B0OFF 12352
#define B1OFF 12372
#define B2OFF 12404
#define B3OFF 12468
#define WREPSZ 12496

// fc01: samples per block
#define FCNS 2

// ---------------------------------------------------------------------------
// Weight repack
// ---------------------------------------------------------------------------
__device__ __forceinline__ void pack_one(int idx, int OC, int IC, int OCG,
                                         int OPG, int WSTR,
                                         const float* __restrict__ w,
                                         float* __restrict__ dst)
{
    if (idx >= OCG * IC * WSTR) return;
    int ocg = idx / (IC * WSTR);
    int r   = idx - ocg * (IC * WSTR);
    int ic  = r / WSTR;
    int q   = r - ic * WSTR;
    int o   = q / 3, k = q - o * 3;
    int oc  = ocg * OPG + o;
    dst[idx] = (o < OPG && oc < OC) ? w[(oc * IC + ic) * 3 + k] : 0.f;
}

__global__ __launch_bounds__(256) void repack_kernel(
    const float* __restrict__ w0, const float* __restrict__ b0,
    const float* __restrict__ w1, const float* __restrict__ b1,
    const float* __restrict__ w2, const float* __restrict__ b2,
    const float* __restrict__ w3, const float* __restrict__ b3,
    float* __restrict__ wrep)
{
    int idx = blockIdx.x * 256 + threadIdx.x;
    pack_one(idx, 20,  3, 4, 5, 16, w0, wrep + W0OFF);
    pack_one(idx, 32, 20, 4, 8, 24, w1, wrep + W1OFF);
    pack_one(idx, 64, 32, 8, 8, 24, w2, wrep + W2OFF);
    pack_one(idx, 20, 64, 4, 5, 16, w3, wrep + W3OFF);
    if (idx < 20)            wrep[B0OFF + idx] = b0[idx];
    else if (idx < 52)  { int i = idx - 20;  wrep[B1OFF + i] = b1[i]; }
    else if (idx < 116) { int i = idx - 52;  wrep[B2OFF + i] = b2[i]; }
    else if (idx < 136) { int i = idx - 116; wrep[B3OFF + i] = b3[i]; }
}

// ---------------------------------------------------------------------------
// One conv(K=3,SAME)+ReLU+pool2 stage on even/odd-split LDS buffers.
// R6: explicit 4-deep software pipeline over ic. Each task preloads
// ic=0..3 (weights via VMEM, inputs via DS), then the main loop does
// FMA(buf[ic&3]) followed by the loads for ic+4 into the same slot.
// Use-after-issue distance = 3 bursts -> per-wave period >= L/3, so
// 3 waves/SIMD saturate VALU instead of stalling on vmcnt+lgkm drains.
// ---------------------------------------------------------------------------
template<int IC, int OC, int OCG, int OPG, int WSTR, int JOUT, int LG, bool FINAL>
__device__ __forceinline__ void stage_eo(const float* __restrict__ in,
                                         float* __restrict__ out,
                                         float* __restrict__ outg,
                                         const float* __restrict__ wrep,
                                         const float* __restrict__ brep,
                                         int pbase, int o3, int wv, int lane,
                                         int zero)
{
    constexpr int PIN  = JOUT + 1;
    constexpr int POUT = JOUT / 2;
    constexpr int NJT  = (JOUT + 63) / 64;
    constexpr int TPW  = (OCG * NJT) / 4;   // integer for all four stages
    constexpr int NB   = 4;
    constexpr int MAIN = (IC > NB) ? (IC - NB) : 0;   // 0,16,28,60 (all %4==0)
#pragma unroll
    for (int t = 0; t < TPW; ++t) {
        const int task = wv * TPW + t;
        const int ocg = task / NJT;                 // wave-uniform
        const int jt  = task - ocg * NJT;
        const int j   = jt * 64 + lane;
        const int jc  = (j < JOUT) ? j : (JOUT - 1);
        const int g   = pbase + j;
        const bool val = (j < JOUT) && (g >= 0) && (g < LG);
        const float* bp = brep + ocg * OPG;
        float ae[OPG], ao[OPG];
#pragma unroll
        for (int o = 0; o < OPG; ++o) { ae[o] = bp[o]; ao[o] = ae[o]; }
        const float* wbase = wrep + ocg * (IC * WSTR) + zero;  // stays VMEM

        // ---- pipeline buffers ----
        float wbuf[NB][WSTR];
        float ebuf[NB][2], obuf[NB][2];
#pragma unroll
        for (int p = 0; p < NB; ++p) {
            if (p < IC) {
                const float* wp = wbase + p * WSTR;
#pragma unroll
                for (int q = 0; q < WSTR / 4; ++q)
                    *(float4*)&wbuf[p][q * 4] = *(const float4*)(wp + q * 4);
                const float* ip = in + p * (2 * PIN);
                __builtin_memcpy(&ebuf[p][0], ip + jc, 8);
                __builtin_memcpy(&obuf[p][0], ip + PIN + jc, 8);
            }
        }
        // ---- main pipelined loop ----
#pragma unroll 4
        for (int ic = 0; ic < MAIN; ++ic) {
            const int s = ic & 3;
            {
                const float e0 = ebuf[s][0], e1 = ebuf[s][1];
                const float o0 = obuf[s][0], o1 = obuf[s][1];
#pragma unroll
                for (int o = 0; o < OPG; ++o) {
                    const float w0 = wbuf[s][o*3+0], w1 = wbuf[s][o*3+1], w2 = wbuf[s][o*3+2];
                    ae[o] = fmaf(e0, w0, fmaf(o0, w1, fmaf(e1, w2, ae[o])));
                    ao[o] = fmaf(o0, w0, fmaf(e1, w1, fmaf(o1, w2, ao[o])));
                }
            }
            const int icn = ic + NB;
            const float* wp = wbase + icn * WSTR;
#pragma unroll
            for (int q = 0; q < WSTR / 4; ++q)
                *(float4*)&wbuf[s][q * 4] = *(const float4*)(wp + q * 4);
            const float* ip = in + icn * (2 * PIN);
            __builtin_memcpy(&ebuf[s][0], ip + jc, 8);
            __builtin_memcpy(&obuf[s][0], ip + PIN + jc, 8);
        }
        // ---- tail (no prefetch) ----
#pragma unroll
        for (int ic = MAIN; ic < IC; ++ic) {
            const int s = ic & 3;
            const float e0 = ebuf[s][0], e1 = ebuf[s][1];
            const float o0 = obuf[s][0], o1 = obuf[s][1];
#pragma unroll
            for (int o = 0; o < OPG; ++o) {
                const float w0 = wbuf[s][o*3+0], w1 = wbuf[s][o*3+1], w2 = wbuf[s][o*3+2];
                ae[o] = fmaf(e0, w0, fmaf(o0, w1, fmaf(e1, w2, ae[o])));
                ao[o] = fmaf(o0, w0, fmaf(e1, w1, fmaf(o1, w2, ao[o])));
            }
        }
        if constexpr (FINAL) {
            const int gj = o3 + j;
            if (gj < 375 && j < JOUT) {
#pragma unroll
                for (int o = 0; o < OPG; ++o)
                    outg[(ocg*OPG+o) * 375 + gj] = fmaxf(fmaxf(ae[o], ao[o]), 0.f);
            }
        } else {
            if (j < JOUT) {
                float* dst = out + ((j & 1) ? POUT : 0) + (j >> 1);
#pragma unroll
                for (int o = 0; o < OPG; ++o)
                    dst[(ocg*OPG+o) * JOUT] = val ? fmaxf(fmaxf(ae[o], ao[o]), 0.f) : 0.f;
            }
        }
    }
}

__global__ __launch_bounds__(256, 3) void conv_chain_eo(
    const float* __restrict__ x,
    const float* __restrict__ wrep,
    float* __restrict__ hcat)
{
    __shared__ float A[ASZ];
    __shared__ float B[BSZ];

    const int tid  = threadIdx.x;
    const int wv   = __builtin_amdgcn_readfirstlane(tid >> 6);
    const int lane = tid & 63;
    // opaque zero: compiler can't prove uniformity -> weight loads stay VMEM
    const int zero = __builtin_amdgcn_ds_bpermute(0, 0);
    const int n     = blockIdx.x / NCHK;
    const int chunk = blockIdx.x % NCHK;
    const int o3 = chunk * TCH;
    const int p2 = 2*o3 - 1, p1 = 4*o3 - 3, p0 = 8*o3 - 7, xs = 16*o3 - 15;

    // stage x -> A in even/odd split (3 ch, 367 pairs, plane stride 734)
    const float* xn = x + (size_t)n * 3 * LIN;
    for (int idx = tid; idx < 3 * 734; idx += 256) {
        int c = idx / 734, i = idx - c * 734;
        int g = xs + i;
        float v = (g >= 0 && g < LIN) ? xn[c * LIN + g] : 0.f;
        A[c * 734 + ((i & 1) ? 367 : 0) + (i >> 1)] = v;
    }
    __syncthreads();
    stage_eo< 3, 20, 4, 5, 16, 366, 3000, false>(A, B, nullptr, wrep + W0OFF, wrep + B0OFF, p0, o3, wv, lane, zero);
    __syncthreads();
    stage_eo<20, 32, 4, 8, 24, 182, 1500, false>(B, A, nullptr, wrep + W1OFF, wrep + B1OFF, p1, o3, wv, lane, zero);
    __syncthreads();
    stage_eo<32, 64, 8, 8, 24,  90,  750, false>(A, B, nullptr, wrep + W2OFF, wrep + B2OFF, p2, o3, wv, lane, zero);
    __syncthreads();
    stage_eo<64, 20, 4, 5, 16,  44,  375, true >(B, nullptr, hcat + (size_t)n * HCATW,
                                                 wrep + W3OFF, wrep + B3OFF, o3, o3, wv, lane, zero);
}

// ---------------------------------------------------------------------------
// LAPACK ssyevd (n=3, uplo='L') replica: ssytrd -> ssteqr('I') -> apply Q.
// ---------------------------------------------------------------------------
__device__ __forceinline__ float fsign(float a, float b) {
    return (b >= 0.0f) ? fabsf(a) : -fabsf(a);
}
__device__ __forceinline__ float slapy2(float xx, float yy) {
    float xa = fabsf(xx), ya = fabsf(yy);
    float w = fmaxf(xa, ya), z = fminf(xa, ya);
    if (z == 0.f) return w;
    float t = z / w;
    return w * sqrtf(1.f + t*t);
}
// LAPACK 3.10+ slartg: c >= 0 always, r = sign(f)*hypot
__device__ __forceinline__ void slartg(float f, float g, float& c, float& s, float& r) {
    if (g == 0.f)      { c = 1.f; s = 0.f; r = f; }
    else if (f == 0.f) { c = 0.f; s = (g >= 0.f ? 1.f : -1.f); r = fabsf(g); }
    else {
        float d = sqrtf(f*f + g*g);
        c = fabsf(f) / d;
        r = fsign(d, f);
        s = g / r;
    }
}
__device__ void slaev2(float a, float b, float cc,
                       float& rt1, float& rt2, float& cs1, float& sn1) {
    float sm = a + cc, df = a - cc;
    float adf = fabsf(df);
    float tb = b + b, ab = fabsf(tb);
    float acmx, acmn;
    if (fabsf(a) > fabsf(cc)) { acmx = a; acmn = cc; } else { acmx = cc; acmn = a; }
    float rt;
    if (adf > ab)      { float t = ab/adf; rt = adf*sqrtf(1.f + t*t); }
    else if (adf < ab) { float t = adf/ab; rt = ab*sqrtf(1.f + t*t); }
    else rt = ab * sqrtf(2.f);
    int sgn1;
    if (sm < 0.f)      { rt1 = 0.5f*(sm - rt); sgn1 = -1; rt2 = (acmx/rt1)*acmn - (b/rt1)*b; }
    else if (sm > 0.f) { rt1 = 0.5f*(sm + rt); sgn1 =  1; rt2 = (acmx/rt1)*acmn - (b/rt1)*b; }
    else               { rt1 = 0.5f*rt; rt2 = -0.5f*rt; sgn1 = 1; }
    float cs; int sgn2;
    if (df >= 0.f) { cs = df + rt; sgn2 = 1; } else { cs = df - rt; sgn2 = -1; }
    float acs = fabsf(cs);
    if (acs > ab) {
        float ct = -tb / cs;
        sn1 = 1.f / sqrtf(1.f + ct*ct);
        cs1 = ct * sn1;
    } else {
        if (ab == 0.f) { cs1 = 1.f; sn1 = 0.f; }
        else {
            float tn = -cs / tb;
            cs1 = 1.f / sqrtf(1.f + tn*tn);
            sn1 = tn * cs1;
        }
    }
    if (sgn1 == sgn2) { float tn = cs1; cs1 = -sn1; sn1 = tn; }
}
__device__ __forceinline__ void rot_cols(float z[3][3], int jc, float c, float s) {
    for (int i = 0; i < 3; ++i) {
        float t = z[i][jc+1];
        z[i][jc+1] = c*t - s*z[i][jc];
        z[i][jc]   = s*t + c*z[i][jc];
    }
}

__device__ void ssteqr3(float d[3], float e[2], float z[3][3]) {
    const float eps    = 5.9604645e-8f;
    const float eps2   = eps * eps;
    const float safmin = 1.17549435e-38f;
    const int n = 3;
    for (int i = 0; i < 3; ++i)
        for (int j = 0; j < 3; ++j) z[i][j] = (i == j) ? 1.f : 0.f;
    const int nmaxit = n * 30;
    int jtot = 0;
    float cw[2], sw[2];
    int l1 = 1, l, m, lend, lsv, lendsv;

L10:
    if (l1 > n) goto L160;
    if (l1 > 1) e[l1-2] = 0.f;
    if (l1 <= n-1) {
        for (m = l1; m <= n-1; ++m) {
            float tst = fabsf(e[m-1]);
            if (tst == 0.f) goto L30;
            if (tst <= (sqrtf(fabsf(d[m-1])) * sqrtf(fabsf(d[m]))) * eps) {
                e[m-1] = 0.f;
                goto L30;
            }
        }
    }
    m = n;
L30:
    l = l1; lsv = l; lend = m; lendsv = lend; l1 = m + 1;
    if (lend == l) goto L10;
    if (fabsf(d[lend-1]) < fabsf(d[l-1])) { lend = lsv; l = lendsv; }
    if (lend > l) {
L40:
        if (l != lend) {
            bool found = false;
            for (m = l; m <= lend-1; ++m) {
                float tst = e[m-1]*e[m-1];
                if (tst <= (eps2*fabsf(d[m-1]))*fabsf(d[m]) + safmin) { found = true; break; }
            }
            if (!found) m = lend;
        } else m = lend;
        if (m < lend) e[m-1] = 0.f;
        {
            float p = d[l-1];
            if (m == l) {
                d[l-1] = p;
                l = l + 1;
                if (l <= lend) goto L40;
                goto L140;
            }
            if (m == l+1) {
                float rt1, rt2, c2, s2;
                slaev2(d[l-1], e[l-1], d[l], rt1, rt2, c2, s2);
                rot_cols(z, l-1, c2, s2);
                d[l-1] = rt1; d[l] = rt2; e[l-1] = 0.f;
                l += 2;
                if (l <= lend) goto L40;
                goto L140;
            }
            if (jtot == nmaxit) goto L140;
            jtot++;
            float g = (d[l] - p) / (2.f * e[l-1]);
            float r = slapy2(g, 1.f);
            g = d[m-1] - p + e[l-1] / (g + fsign(r, g));
            float s = 1.f, c = 1.f;
            p = 0.f;
            for (int i = m-1; i >= l; --i) {
                float f = s * e[i-1];
                float b = c * e[i-1];
                slartg(g, f, c, s, r);
                if (i != m-1) e[i] = r;
                g = d[i] - p;
                r = (d[i-1] - g)*s + 2.f*c*b;
                p = s * r;
                d[i] = g + p;
                g = c*r - b;
                cw[i-l] = c; sw[i-l] = -s;
            }
            for (int jj = m-l; jj >= 1; --jj)
                rot_cols(z, l + jj - 2, cw[jj-1], sw[jj-1]);
            d[l-1] = d[l-1] - p;
            e[l-1] = g;
            goto L40;
        }
    } else {
L90:
        if (l != lend) {
            bool found = false;
            for (m = l; m >= lend+1; --m) {
                float tst = e[m-2]*e[m-2];
                if (tst <= (eps2*fabsf(d[m-1]))*fabsf(d[m-2]) + safmin) { found = true; break; }
            }
            if (!found) m = lend;
        } else m = lend;
        if (m > lend) e[m-2] = 0.f;
        {
            float p = d[l-1];
            if (m == l) {
                d[l-1] = p;
                l = l - 1;
                if (l >= lend) goto L90;
                goto L140;
            }
            if (m == l-1) {
                float rt1, rt2, c2, s2;
                slaev2(d[l-2], e[l-2], d[l-1], rt1, rt2, c2, s2);
                rot_cols(z, l-2, c2, s2);
                d[l-2] = rt1; d[l-1] = rt2; e[l-2] = 0.f;
                l -= 2;
                if (l >= lend) goto L90;
                goto L140;
            }
            if (jtot == nmaxit) goto L140;
            jtot++;
            float g = (d[l-2] - p) / (2.f * e[l-2]);
            float r = slapy2(g, 1.f);
            g = d[m-1] - p + e[l-2] / (g + fsign(r, g));
            float s = 1.f, c = 1.f;
            p = 0.f;
            for (int i = m; i <= l-1; ++i) {
                float f = s * e[i-1];
                float b = c * e[i-1];
                slartg(g, f, c, s, r);
                if (i != m) e[i-2] = r;
                g = d[i-1] - p;
                r = (d[i] - g)*s + 2.f*c*b;
                p = s * r;
                d[i-1] = g + p;
                g = c*r - b;
                cw[i-m] = c; sw[i-m] = s;
            }
            for (int jj = 1; jj <= l-m; ++jj)
                rot_cols(z, m + jj - 2, cw[jj-1], sw[jj-1]);
            d[l-1] = d[l-1] - p;
            e[l-2] = g;
            goto L90;
        }
    }
L140:
    if (jtot < nmaxit) goto L10;
L160:
    for (int ii = 2; ii <= n; ++ii) {
        int i = ii - 1, k = i;
        float p = d[i-1];
        for (int j = ii; j <= n; ++j)
            if (d[j-1] < p) { k = j; p = d[j-1]; }
        if (k != i) {
            d[k-1] = d[i-1]; d[i-1] = p;
            for (int r0 = 0; r0 < 3; ++r0) {
                float t = z[r0][i-1]; z[r0][i-1] = z[r0][k-1]; z[r0][k-1] = t;
            }
        }
    }
}

// ---------------------------------------------------------------------------
// cov + eig kernel
// ---------------------------------------------------------------------------
__global__ __launch_bounds__(256) void cov_eig_kernel(const float* __restrict__ x,
                                                      float* __restrict__ eigbuf,
                                                      unsigned int* __restrict__ gmax)
{
    __shared__ float part[4][9];
    const int n = blockIdx.x;
    const float* xn = x + (size_t)n * 3 * LIN;
    float v[9] = {0,0,0,0,0,0,0,0,0};
    for (int l = threadIdx.x; l < LIN; l += 256) {
        float a = xn[l], b = xn[LIN + l], c = xn[2*LIN + l];
        v[0] += a; v[1] += b; v[2] += c;
        v[3] = fmaf(a,a,v[3]); v[4] = fmaf(a,b,v[4]); v[5] = fmaf(a,c,v[5]);
        v[6] = fmaf(b,b,v[6]); v[7] = fmaf(b,c,v[7]); v[8] = fmaf(c,c,v[8]);
    }
#pragma unroll
    for (int off = 32; off > 0; off >>= 1)
#pragma unroll
        for (int i = 0; i < 9; ++i) v[i] += __shfl_down(v[i], off, 64);
    const int wv = threadIdx.x >> 6, lane = threadIdx.x & 63;
    if (lane == 0)
        for (int i = 0; i < 9; ++i) part[wv][i] = v[i];
    __syncthreads();
    if (threadIdx.x == 0) {
        float t[9];
        for (int i = 0; i < 9; ++i)
            t[i] = part[0][i] + part[1][i] + part[2][i] + part[3][i];
        const float Lf = (float)LIN;
        float m0 = t[0]/Lf, m1 = t[1]/Lf, m2 = t[2]/Lf;
        float c00 = (t[3] - Lf*m0*m0) / (Lf - 1.f);
        float c01 = (t[4] - Lf*m0*m1) / (Lf - 1.f);
        float c02 = (t[5] - Lf*m0*m2) / (Lf - 1.f);
        float c11 = (t[6] - Lf*m1*m1) / (Lf - 1.f);
        float c12 = (t[7] - Lf*m1*m2) / (Lf - 1.f);
        float c22 = (t[8] - Lf*m2*m2) / (Lf - 1.f);

        float dd[3], ee[2], tau, v2;
        {
            float a21 = c01, a31 = c02, a22 = c11, a32 = c12, a33 = c22;
            float xnorm = fabsf(a31);
            if (xnorm == 0.f) {
                tau = 0.f; v2 = 0.f;
                dd[0] = c00; dd[1] = a22; dd[2] = a33;
                ee[0] = a21; ee[1] = a32;
            } else {
                float beta = -fsign(slapy2(a21, xnorm), a21);
                tau = (beta - a21) / beta;
                v2  = a31 / (a21 - beta);
                ee[0] = beta;
                float x1 = tau*(a22 + a32*v2);
                float x2 = tau*(a32 + a33*v2);
                float al = -0.5f*tau*(x1 + x2*v2);
                float w1 = x1 + al;
                float w2 = x2 + al*v2;
                a22 -= 2.f*w1;
                a32 -= (v2*w1 + w2);
                a33 -= 2.f*v2*w2;
                dd[0] = c00; dd[1] = a22; dd[2] = a33;
                ee[1] = a32;
            }
        }
        float zz[3][3];
        ssteqr3(dd, ee, zz);
        if (tau != 0.f) {
            for (int j = 0; j < 3; ++j) {
                float sum = zz[1][j] + v2*zz[2][j];
                zz[1][j] -= tau * sum;
                zz[2][j] -= tau * v2 * sum;
            }
        }

        float* eb = eigbuf + n * 21;
        eb[0] = c00; eb[1] = c01; eb[2] = c02;
        eb[3] = c01; eb[4] = c11; eb[5] = c12;
        eb[6] = c02; eb[7] = c12; eb[8] = c22;
        eb[9] = dd[0]; eb[10] = dd[1]; eb[11] = dd[2];
        for (int c = 0; c < 3; ++c)
            for (int k = 0; k < 3; ++k) eb[12 + c*3 + k] = zz[c][k];

        float vmax = fmaxf(dd[0], fmaxf(dd[1], dd[2]));
        float cmax = 0.f;
        for (int i = 0; i < 9; ++i) cmax = fmaxf(cmax, fabsf(eb[i]));
        atomicMax(&gmax[0], __float_as_uint(vmax));
        atomicMax(&gmax[1], __float_as_uint(cmax));
    }
}

// ---------------------------------------------------------------------------
// feats -> 1x1 conv (wc) + relu, writes hcat[:, 7500:7640]
// ---------------------------------------------------------------------------
__global__ __launch_bounds__(256) void feats_kernel(const float* __restrict__ eigbuf,
                                                    const unsigned int* __restrict__ gmax,
                                                    const float* __restrict__ wc,
                                                    const float* __restrict__ bc,
                                                    float* __restrict__ hcat)
{
    const int n = blockIdx.x;
    const int t = threadIdx.x;
    if (t >= 140) return;
    const int o = t / 7, j = t % 7;
    const float* eb = eigbuf + n * 21;
    const float vmax = __uint_as_float(gmax[0]);
    const float cmax = __uint_as_float(gmax[1]);
    float f0, f1, f2;
    if (j < 3)       { f0 = eb[0*3+j]/cmax; f1 = eb[1*3+j]/cmax; f2 = eb[2*3+j]/cmax; }
    else if (j == 3) { f0 = eb[9]/vmax;     f1 = eb[10]/vmax;    f2 = eb[11]/vmax; }
    else             { int k = j-4; f0 = eb[12+0*3+k]; f1 = eb[12+1*3+k]; f2 = eb[12+2*3+k]; }
    float r = bc[o] + wc[o*3+0]*f0 + wc[o*3+1]*f1 + wc[o*3+2]*f2;
    hcat[(size_t)n*HCATW + 7500 + o*7 + j] = fmaxf(r, 0.f);
}

// ---------------------------------------------------------------------------
// FC0+FC1 fused, 2 samples per block, h staged in LDS:
// h = relu(hcat @ wl0^T + bl0); out = h @ wl1^T + bl1.
// ---------------------------------------------------------------------------
__global__ __launch_bounds__(256) void fc01_kernel(const float* __restrict__ hcat,
                                                   const float* __restrict__ wl0,
                                                   const float* __restrict__ bl0,
                                                   const float* __restrict__ wl1,
                                                   const float* __restrict__ bl1,
                                                   float* __restrict__ out)
{
    __shared__ float hl[FCNS * HCATW];     // 61120 B
    __shared__ float hbuf[FCNS * HID];
    const int tid = threadIdx.x;
    const int n0 = blockIdx.x * FCNS;
    for (int i = tid; i < FCNS * (HCATW/4); i += 256) {
        int s  = i / (HCATW/4);
        int k4 = i - s * (HCATW/4);
        ((float4*)hl)[s * (HCATW/4) + k4] =
            *(const float4*)(hcat + (size_t)(n0 + s) * HCATW + k4 * 4);
    }
    __syncthreads();
    const int wv = tid >> 6;
    const int lane = tid & 63;
    for (int o = wv; o < HID; o += 4) {
        const float* w = wl0 + (size_t)o * HCATW;
        float a0 = 0.f, a1 = 0.f;
        for (int k = lane*4; k < HCATW; k += 256) {
            const float4 w4 = *(const float4*)(w + k);
            const float4 h0 = *(const float4*)(hl + k);
            const float4 h1 = *(const float4*)(hl + HCATW + k);
            a0 = fmaf(h0.x, w4.x, a0); a0 = fmaf(h0.y, w4.y, a0);
            a0 = fmaf(h0.z, w4.z, a0); a0 = fmaf(h0.w, w4.w, a0);
            a1 = fmaf(h1.x, w4.x, a1); a1 = fmaf(h1.y, w4.y, a1);
            a1 = fmaf(h1.z, w4.z, a1); a1 = fmaf(h1.w, w4.w, a1);
        }
#pragma unroll
        for (int off = 32; off > 0; off >>= 1) {
            a0 += __shfl_down(a0, off, 64);
            a1 += __shfl_down(a1, off, 64);
        }
        if (lane == 0) {
            hbuf[o]       = fmaxf(a0 + bl0[o], 0.f);
            hbuf[HID + o] = fmaxf(a1 + bl0[o], 0.f);
        }
    }
    __syncthreads();
    if (tid < 2 * FCNS) {
        const int s = tid >> 1, r = tid & 1;
        const float* w = wl1 + r * HID;
        float acc = bl1[r];
        for (int k = 0; k < HID; ++k) acc = fmaf(hbuf[s * HID + k], w[k], acc);
        out[r * NBATCH + n0 + s] = acc;
    }
}

// ---------------------------------------------------------------------------
// launch
// ---------------------------------------------------------------------------
extern "C" void kernel_launch(void* const* d_in, const int* in_sizes, int n_in,
                              void* d_out, int out_size, void* d_ws, size_t ws_size,
                              hipStream_t stream)
{
    const float* x   = (const float*)d_in[0];
    const float* w0  = (const float*)d_in[1];
    const float* b0  = (const float*)d_in[2];
    const float* w1  = (const float*)d_in[3];
    const float* b1  = (const float*)d_in[4];
    const float* w2  = (const float*)d_in[5];
    const float* b2  = (const float*)d_in[6];
    const float* w3  = (const float*)d_in[7];
    const float* b3  = (const float*)d_in[8];
    const float* wc  = (const float*)d_in[9];
    const float* bc  = (const float*)d_in[10];
    const float* wl0 = (const float*)d_in[11];
    const float* bl0 = (const float*)d_in[12];
    const float* wl1 = (const float*)d_in[13];
    const float* bl1 = (const float*)d_in[14];
    float* out = (float*)d_out;

    // workspace layout (floats)
    const size_t HCAT_N = (size_t)NBATCH * HCATW;        // 7,823,360
    const size_t EIG_N  = (size_t)NBATCH * 21;
    const size_t need_bytes = (HCAT_N + EIG_N + 4 + WREPSZ) * 4 + 16;
    if (ws_size < need_bytes) return;

    float* ws     = (float*)d_ws;
    float* hcat   = ws;
    float* eigbuf = hcat + HCAT_N;
    unsigned int* gmax = (unsigned int*)(eigbuf + EIG_N);
    float* wrep   = (float*)(gmax + 4);

    hipMemsetAsync(gmax, 0, 2 * sizeof(unsigned int), stream);

    repack_kernel<<<24, 256, 0, stream>>>(w0, b0, w1, b1, w2, b2, w3, b3, wrep);
    conv_chain_eo<<<NBATCH * NCHK, 256, 0, stream>>>(x, wrep, hcat);
    cov_eig_kernel<<<NBATCH, 256, 0, stream>>>(x, eigbuf, gmax);
    feats_kernel<<<NBATCH, 256, 0, stream>>>(eigbuf, gmax, wc, bc, hcat);
    fc01_kernel<<<NBATCH / FCNS, 256, 0, stream>>>(hcat, wl0, bl0, wl1, bl1, out);
}

// Round 7
// 794.876 us; speedup vs baseline: 2.2718x; 2.2718x over previous
//
#include <hip/hip_runtime.h>
#include <hip/hip_bf16.h>
#include <math.h>

// ---------------------------------------------------------------------------
// Problem constants
// ---------------------------------------------------------------------------
#define NBATCH 1024
#define LIN    6000
#define HCATW  7640       // 20*375 + 20*7
#define HID    100

// conv-chain chunking: T=44 final(375-res) positions per block, 9 chunks
#define TCH   44
#define NCHK  9

#define ASZ 5824            // max(x-buf 3*734=2202, s1-out 32*182=5824)
#define BSZ 7320            // max(s0-out 20*366=7320, s2-out 64*90=5760)

// repacked-weight offsets (floats) inside wrep
#define W0OFF 0             // 4ocg*3ic*16  = 192
#define W1OFF 192           // 4*20*24      = 1920
#define W2OFF 2112          // 8*32*24      = 6144
#define W3OFF 8256          // 4*64*16      = 4096
#define B0OFF 12352
#define B1OFF 12372
#define B2OFF 12404
#define B3OFF 12468
#define WREPSZ 12496

// fc01: samples per block
#define FCNS 4

// ---------------------------------------------------------------------------
// Weight repack
// ---------------------------------------------------------------------------
__device__ __forceinline__ void pack_one(int idx, int OC, int IC, int OCG,
                                         int OPG, int WSTR,
                                         const float* __restrict__ w,
                                         float* __restrict__ dst)
{
    if (idx >= OCG * IC * WSTR) return;
    int ocg = idx / (IC * WSTR);
    int r   = idx - ocg * (IC * WSTR);
    int ic  = r / WSTR;
    int q   = r - ic * WSTR;
    int o   = q / 3, k = q - o * 3;
    int oc  = ocg * OPG + o;
    dst[idx] = (o < OPG && oc < OC) ? w[(oc * IC + ic) * 3 + k] : 0.f;
}

__global__ __launch_bounds__(256) void repack_kernel(
    const float* __restrict__ w0, const float* __restrict__ b0,
    const float* __restrict__ w1, const float* __restrict__ b1,
    const float* __restrict__ w2, const float* __restrict__ b2,
    const float* __restrict__ w3, const float* __restrict__ b3,
    float* __restrict__ wrep)
{
    int idx = blockIdx.x * 256 + threadIdx.x;
    pack_one(idx, 20,  3, 4, 5, 16, w0, wrep + W0OFF);
    pack_one(idx, 32, 20, 4, 8, 24, w1, wrep + W1OFF);
    pack_one(idx, 64, 32, 8, 8, 24, w2, wrep + W2OFF);
    pack_one(idx, 20, 64, 4, 5, 16, w3, wrep + W3OFF);
    if (idx < 20)            wrep[B0OFF + idx] = b0[idx];
    else if (idx < 52)  { int i = idx - 20;  wrep[B1OFF + i] = b1[i]; }
    else if (idx < 116) { int i = idx - 52;  wrep[B2OFF + i] = b2[i]; }
    else if (idx < 136) { int i = idx - 116; wrep[B3OFF + i] = b3[i]; }
}

// ---------------------------------------------------------------------------
// One conv(K=3,SAME)+ReLU+pool2 stage on even/odd-split LDS buffers.
// R7: R5 inner loop (NO rotation buffers — R6 showed they explode VALU),
// 8 waves per block (512 threads), wave-strided tasks. Weights via VMEM
// (vmcnt) so the DS/SMEM lgkm counter only carries activation reads.
// ---------------------------------------------------------------------------
template<int IC, int OC, int OCG, int OPG, int WSTR, int JOUT, int LG, bool FINAL>
__device__ __forceinline__ void stage_eo(const float* __restrict__ in,
                                         float* __restrict__ out,
                                         float* __restrict__ outg,
                                         const float* __restrict__ wrep,
                                         const float* __restrict__ brep,
                                         int pbase, int o3, int wv, int lane,
                                         int zero)
{
    constexpr int PIN  = JOUT + 1;
    constexpr int POUT = JOUT / 2;
    constexpr int NJT  = (JOUT + 63) / 64;
    for (int task = wv; task < OCG * NJT; task += 8) {
        const int ocg = task / NJT;                 // wave-uniform (wv uniform)
        const int jt  = task - ocg * NJT;
        const int j   = jt * 64 + lane;
        const int jc  = (j < JOUT) ? j : (JOUT - 1);
        const int g   = pbase + j;
        const bool val = (j < JOUT) && (g >= 0) && (g < LG);
        const float* bp = brep + ocg * OPG;
        float ae[OPG], ao[OPG];
#pragma unroll
        for (int o = 0; o < OPG; ++o) { ae[o] = bp[o]; ao[o] = ae[o]; }
        const float* wbase = wrep + ocg * (IC * WSTR) + zero;  // stays VMEM
#pragma unroll 2
        for (int ic = 0; ic < IC; ++ic) {
            const float* ip = in + ic * (2 * PIN);
            float2 ev, ov;
            __builtin_memcpy(&ev, ip + jc, 8);        // ds_read2_b32
            __builtin_memcpy(&ov, ip + PIN + jc, 8);  // ds_read2_b32
            const float e0 = ev.x, e1 = ev.y;
            const float o0 = ov.x, o1 = ov.y;
            const float* wp = wbase + ic * WSTR;
            float wr[WSTR];
#pragma unroll
            for (int q = 0; q < WSTR / 4; ++q)
                *(float4*)&wr[q * 4] = *(const float4*)(wp + q * 4);
#pragma unroll
            for (int o = 0; o < OPG; ++o) {
                const float w0 = wr[o*3+0], w1 = wr[o*3+1], w2 = wr[o*3+2];
                ae[o] = fmaf(e0, w0, fmaf(o0, w1, fmaf(e1, w2, ae[o])));
                ao[o] = fmaf(o0, w0, fmaf(e1, w1, fmaf(o1, w2, ao[o])));
            }
        }
        if constexpr (FINAL) {
            const int gj = o3 + j;
            if (gj < 375 && j < JOUT) {
#pragma unroll
                for (int o = 0; o < OPG; ++o)
                    outg[(ocg*OPG+o) * 375 + gj] = fmaxf(fmaxf(ae[o], ao[o]), 0.f);
            }
        } else {
            if (j < JOUT) {
                float* dst = out + ((j & 1) ? POUT : 0) + (j >> 1);
#pragma unroll
                for (int o = 0; o < OPG; ++o)
                    dst[(ocg*OPG+o) * JOUT] = val ? fmaxf(fmaxf(ae[o], ao[o]), 0.f) : 0.f;
            }
        }
    }
}

__global__ __launch_bounds__(512, 6) void conv_chain_eo(
    const float* __restrict__ x,
    const float* __restrict__ wrep,
    float* __restrict__ hcat)
{
    __shared__ float A[ASZ];
    __shared__ float B[BSZ];

    const int tid  = threadIdx.x;
    const int wv   = __builtin_amdgcn_readfirstlane(tid >> 6);
    const int lane = tid & 63;
    // opaque zero: compiler can't prove uniformity -> weight loads stay VMEM
    const int zero = __builtin_amdgcn_ds_bpermute(0, 0);
    const int n     = blockIdx.x / NCHK;
    const int chunk = blockIdx.x % NCHK;
    const int o3 = chunk * TCH;
    const int p2 = 2*o3 - 1, p1 = 4*o3 - 3, p0 = 8*o3 - 7, xs = 16*o3 - 15;

    // stage x -> A in even/odd split (3 ch, 367 pairs, plane stride 734)
    const float* xn = x + (size_t)n * 3 * LIN;
    for (int idx = tid; idx < 3 * 734; idx += 512) {
        int c = idx / 734, i = idx - c * 734;
        int g = xs + i;
        float v = (g >= 0 && g < LIN) ? xn[c * LIN + g] : 0.f;
        A[c * 734 + ((i & 1) ? 367 : 0) + (i >> 1)] = v;
    }
    __syncthreads();
    stage_eo< 3, 20, 4, 5, 16, 366, 3000, false>(A, B, nullptr, wrep + W0OFF, wrep + B0OFF, p0, o3, wv, lane, zero);
    __syncthreads();
    stage_eo<20, 32, 4, 8, 24, 182, 1500, false>(B, A, nullptr, wrep + W1OFF, wrep + B1OFF, p1, o3, wv, lane, zero);
    __syncthreads();
    stage_eo<32, 64, 8, 8, 24,  90,  750, false>(A, B, nullptr, wrep + W2OFF, wrep + B2OFF, p2, o3, wv, lane, zero);
    __syncthreads();
    stage_eo<64, 20, 4, 5, 16,  44,  375, true >(B, nullptr, hcat + (size_t)n * HCATW,
                                                 wrep + W3OFF, wrep + B3OFF, o3, o3, wv, lane, zero);
}

// ---------------------------------------------------------------------------
// LAPACK ssyevd (n=3, uplo='L') replica: ssytrd -> ssteqr('I') -> apply Q.
// ---------------------------------------------------------------------------
__device__ __forceinline__ float fsign(float a, float b) {
    return (b >= 0.0f) ? fabsf(a) : -fabsf(a);
}
__device__ __forceinline__ float slapy2(float xx, float yy) {
    float xa = fabsf(xx), ya = fabsf(yy);
    float w = fmaxf(xa, ya), z = fminf(xa, ya);
    if (z == 0.f) return w;
    float t = z / w;
    return w * sqrtf(1.f + t*t);
}
// LAPACK 3.10+ slartg: c >= 0 always, r = sign(f)*hypot
__device__ __forceinline__ void slartg(float f, float g, float& c, float& s, float& r) {
    if (g == 0.f)      { c = 1.f; s = 0.f; r = f; }
    else if (f == 0.f) { c = 0.f; s = (g >= 0.f ? 1.f : -1.f); r = fabsf(g); }
    else {
        float d = sqrtf(f*f + g*g);
        c = fabsf(f) / d;
        r = fsign(d, f);
        s = g / r;
    }
}
__device__ void slaev2(float a, float b, float cc,
                       float& rt1, float& rt2, float& cs1, float& sn1) {
    float sm = a + cc, df = a - cc;
    float adf = fabsf(df);
    float tb = b + b, ab = fabsf(tb);
    float acmx, acmn;
    if (fabsf(a) > fabsf(cc)) { acmx = a; acmn = cc; } else { acmx = cc; acmn = a; }
    float rt;
    if (adf > ab)      { float t = ab/adf; rt = adf*sqrtf(1.f + t*t); }
    else if (adf < ab) { float t = adf/ab; rt = ab*sqrtf(1.f + t*t); }
    else rt = ab * sqrtf(2.f);
    int sgn1;
    if (sm < 0.f)      { rt1 = 0.5f*(sm - rt); sgn1 = -1; rt2 = (acmx/rt1)*acmn - (b/rt1)*b; }
    else if (sm > 0.f) { rt1 = 0.5f*(sm + rt); sgn1 =  1; rt2 = (acmx/rt1)*acmn - (b/rt1)*b; }
    else               { rt1 = 0.5f*rt; rt2 = -0.5f*rt; sgn1 = 1; }
    float cs; int sgn2;
    if (df >= 0.f) { cs = df + rt; sgn2 = 1; } else { cs = df - rt; sgn2 = -1; }
    float acs = fabsf(cs);
    if (acs > ab) {
        float ct = -tb / cs;
        sn1 = 1.f / sqrtf(1.f + ct*ct);
        cs1 = ct * sn1;
    } else {
        if (ab == 0.f) { cs1 = 1.f; sn1 = 0.f; }
        else {
            float tn = -cs / tb;
            cs1 = 1.f / sqrtf(1.f + tn*tn);
            sn1 = tn * cs1;
        }
    }
    if (sgn1 == sgn2) { float tn = cs1; cs1 = -sn1; sn1 = tn; }
}
__device__ __forceinline__ void rot_cols(float z[3][3], int jc, float c, float s) {
    for (int i = 0; i < 3; ++i) {
        float t = z[i][jc+1];
        z[i][jc+1] = c*t - s*z[i][jc];
        z[i][jc]   = s*t + c*z[i][jc];
    }
}

__device__ void ssteqr3(float d[3], float e[2], float z[3][3]) {
    const float eps    = 5.9604645e-8f;
    const float eps2   = eps * eps;
    const float safmin = 1.17549435e-38f;
    const int n = 3;
    for (int i = 0; i < 3; ++i)
        for (int j = 0; j < 3; ++j) z[i][j] = (i == j) ? 1.f : 0.f;
    const int nmaxit = n * 30;
    int jtot = 0;
    float cw[2], sw[2];
    int l1 = 1, l, m, lend, lsv, lendsv;

L10:
    if (l1 > n) goto L160;
    if (l1 > 1) e[l1-2] = 0.f;
    if (l1 <= n-1) {
        for (m = l1; m <= n-1; ++m) {
            float tst = fabsf(e[m-1]);
            if (tst == 0.f) goto L30;
            if (tst <= (sqrtf(fabsf(d[m-1])) * sqrtf(fabsf(d[m]))) * eps) {
                e[m-1] = 0.f;
                goto L30;
            }
        }
    }
    m = n;
L30:
    l = l1; lsv = l; lend = m; lendsv = lend; l1 = m + 1;
    if (lend == l) goto L10;
    if (fabsf(d[lend-1]) < fabsf(d[l-1])) { lend = lsv; l = lendsv; }
    if (lend > l) {
L40:
        if (l != lend) {
            bool found = false;
            for (m = l; m <= lend-1; ++m) {
                float tst = e[m-1]*e[m-1];
                if (tst <= (eps2*fabsf(d[m-1]))*fabsf(d[m]) + safmin) { found = true; break; }
            }
            if (!found) m = lend;
        } else m = lend;
        if (m < lend) e[m-1] = 0.f;
        {
            float p = d[l-1];
            if (m == l) {
                d[l-1] = p;
                l = l + 1;
                if (l <= lend) goto L40;
                goto L140;
            }
            if (m == l+1) {
                float rt1, rt2, c2, s2;
                slaev2(d[l-1], e[l-1], d[l], rt1, rt2, c2, s2);
                rot_cols(z, l-1, c2, s2);
                d[l-1] = rt1; d[l] = rt2; e[l-1] = 0.f;
                l += 2;
                if (l <= lend) goto L40;
                goto L140;
            }
            if (jtot == nmaxit) goto L140;
            jtot++;
            float g = (d[l] - p) / (2.f * e[l-1]);
            float r = slapy2(g, 1.f);
            g = d[m-1] - p + e[l-1] / (g + fsign(r, g));
            float s = 1.f, c = 1.f;
            p = 0.f;
            for (int i = m-1; i >= l; --i) {
                float f = s * e[i-1];
                float b = c * e[i-1];
                slartg(g, f, c, s, r);
                if (i != m-1) e[i] = r;
                g = d[i] - p;
                r = (d[i-1] - g)*s + 2.f*c*b;
                p = s * r;
                d[i] = g + p;
                g = c*r - b;
                cw[i-l] = c; sw[i-l] = -s;
            }
            for (int jj = m-l; jj >= 1; --jj)
                rot_cols(z, l + jj - 2, cw[jj-1], sw[jj-1]);
            d[l-1] = d[l-1] - p;
            e[l-1] = g;
            goto L40;
        }
    } else {
L90:
        if (l != lend) {
            bool found = false;
            for (m = l; m >= lend+1; --m) {
                float tst = e[m-2]*e[m-2];
                if (tst <= (eps2*fabsf(d[m-1]))*fabsf(d[m-2]) + safmin) { found = true; break; }
            }
            if (!found) m = lend;
        } else m = lend;
        if (m > lend) e[m-2] = 0.f;
        {
            float p = d[l-1];
            if (m == l) {
                d[l-1] = p;
                l = l - 1;
                if (l >= lend) goto L90;
                goto L140;
            }
            if (m == l-1) {
                float rt1, rt2, c2, s2;
                slaev2(d[l-2], e[l-2], d[l-1], rt1, rt2, c2, s2);
                rot_cols(z, l-2, c2, s2);
                d[l-2] = rt1; d[l-1] = rt2; e[l-2] = 0.f;
                l -= 2;
                if (l >= lend) goto L90;
                goto L140;
            }
            if (jtot == nmaxit) goto L140;
            jtot++;
            float g = (d[l-2] - p) / (2.f * e[l-2]);
            float r = slapy2(g, 1.f);
            g = d[m-1] - p + e[l-2] / (g + fsign(r, g));
            float s = 1.f, c = 1.f;
            p = 0.f;
            for (int i = m; i <= l-1; ++i) {
                float f = s * e[i-1];
                float b = c * e[i-1];
                slartg(g, f, c, s, r);
                if (i != m) e[i-2] = r;
                g = d[i-1] - p;
                r = (d[i] - g)*s + 2.f*c*b;
                p = s * r;
                d[i-1] = g + p;
                g = c*r - b;
                cw[i-m] = c; sw[i-m] = s;
            }
            for (int jj = 1; jj <= l-m; ++jj)
                rot_cols(z, m + jj - 2, cw[jj-1], sw[jj-1]);
            d[l-1] = d[l-1] - p;
            e[l-2] = g;
            goto L90;
        }
    }
L140:
    if (jtot < nmaxit) goto L10;
L160:
    for (int ii = 2; ii <= n; ++ii) {
        int i = ii - 1, k = i;
        float p = d[i-1];
        for (int j = ii; j <= n; ++j)
            if (d[j-1] < p) { k = j; p = d[j-1]; }
        if (k != i) {
            d[k-1] = d[i-1]; d[i-1] = p;
            for (int r0 = 0; r0 < 3; ++r0) {
                float t = z[r0][i-1]; z[r0][i-1] = z[r0][k-1]; z[r0][k-1] = t;
            }
        }
    }
}

// ---------------------------------------------------------------------------
// cov + eig kernel
// ---------------------------------------------------------------------------
__global__ __launch_bounds__(256) void cov_eig_kernel(const float* __restrict__ x,
                                                      float* __restrict__ eigbuf,
                                                      unsigned int* __restrict__ gmax)
{
    __shared__ float part[4][9];
    const int n = blockIdx.x;
    const float* xn = x + (size_t)n * 3 * LIN;
    float v[9] = {0,0,0,0,0,0,0,0,0};
    for (int l = threadIdx.x; l < LIN; l += 256) {
        float a = xn[l], b = xn[LIN + l], c = xn[2*LIN + l];
        v[0] += a; v[1] += b; v[2] += c;
        v[3] = fmaf(a,a,v[3]); v[4] = fmaf(a,b,v[4]); v[5] = fmaf(a,c,v[5]);
        v[6] = fmaf(b,b,v[6]); v[7] = fmaf(b,c,v[7]); v[8] = fmaf(c,c,v[8]);
    }
#pragma unroll
    for (int off = 32; off > 0; off >>= 1)
#pragma unroll
        for (int i = 0; i < 9; ++i) v[i] += __shfl_down(v[i], off, 64);
    const int wv = threadIdx.x >> 6, lane = threadIdx.x & 63;
    if (lane == 0)
        for (int i = 0; i < 9; ++i) part[wv][i] = v[i];
    __syncthreads();
    if (threadIdx.x == 0) {
        float t[9];
        for (int i = 0; i < 9; ++i)
            t[i] = part[0][i] + part[1][i] + part[2][i] + part[3][i];
        const float Lf = (float)LIN;
        float m0 = t[0]/Lf, m1 = t[1]/Lf, m2 = t[2]/Lf;
        float c00 = (t[3] - Lf*m0*m0) / (Lf - 1.f);
        float c01 = (t[4] - Lf*m0*m1) / (Lf - 1.f);
        float c02 = (t[5] - Lf*m0*m2) / (Lf - 1.f);
        float c11 = (t[6] - Lf*m1*m1) / (Lf - 1.f);
        float c12 = (t[7] - Lf*m1*m2) / (Lf - 1.f);
        float c22 = (t[8] - Lf*m2*m2) / (Lf - 1.f);

        float dd[3], ee[2], tau, v2;
        {
            float a21 = c01, a31 = c02, a22 = c11, a32 = c12, a33 = c22;
            float xnorm = fabsf(a31);
            if (xnorm == 0.f) {
                tau = 0.f; v2 = 0.f;
                dd[0] = c00; dd[1] = a22; dd[2] = a33;
                ee[0] = a21; ee[1] = a32;
            } else {
                float beta = -fsign(slapy2(a21, xnorm), a21);
                tau = (beta - a21) / beta;
                v2  = a31 / (a21 - beta);
                ee[0] = beta;
                float x1 = tau*(a22 + a32*v2);
                float x2 = tau*(a32 + a33*v2);
                float al = -0.5f*tau*(x1 + x2*v2);
                float w1 = x1 + al;
                float w2 = x2 + al*v2;
                a22 -= 2.f*w1;
                a32 -= (v2*w1 + w2);
                a33 -= 2.f*v2*w2;
                dd[0] = c00; dd[1] = a22; dd[2] = a33;
                ee[1] = a32;
            }
        }
        float zz[3][3];
        ssteqr3(dd, ee, zz);
        if (tau != 0.f) {
            for (int j = 0; j < 3; ++j) {
                float sum = zz[1][j] + v2*zz[2][j];
                zz[1][j] -= tau * sum;
                zz[2][j] -= tau * v2 * sum;
            }
        }

        float* eb = eigbuf + n * 21;
        eb[0] = c00; eb[1] = c01; eb[2] = c02;
        eb[3] = c01; eb[4] = c11; eb[5] = c12;
        eb[6] = c02; eb[7] = c12; eb[8] = c22;
        eb[9] = dd[0]; eb[10] = dd[1]; eb[11] = dd[2];
        for (int c = 0; c < 3; ++c)
            for (int k = 0; k < 3; ++k) eb[12 + c*3 + k] = zz[c][k];

        float vmax = fmaxf(dd[0], fmaxf(dd[1], dd[2]));
        float cmax = 0.f;
        for (int i = 0; i < 9; ++i) cmax = fmaxf(cmax, fabsf(eb[i]));
        atomicMax(&gmax[0], __float_as_uint(vmax));
        atomicMax(&gmax[1], __float_as_uint(cmax));
    }
}

// ---------------------------------------------------------------------------
// feats -> 1x1 conv (wc) + relu, writes hcat[:, 7500:7640]
// ---------------------------------------------------------------------------
__global__ __launch_bounds__(256) void feats_kernel(const float* __restrict__ eigbuf,
                                                    const unsigned int* __restrict__ gmax,
                                                    const float* __restrict__ wc,
                                                    const float* __restrict__ bc,
                                                    float* __restrict__ hcat)
{
    const int n = blockIdx.x;
    const int t = threadIdx.x;
    if (t >= 140) return;
    const int o = t / 7, j = t % 7;
    const float* eb = eigbuf + n * 21;
    const float vmax = __uint_as_float(gmax[0]);
    const float cmax = __uint_as_float(gmax[1]);
    float f0, f1, f2;
    if (j < 3)       { f0 = eb[0*3+j]/cmax; f1 = eb[1*3+j]/cmax; f2 = eb[2*3+j]/cmax; }
    else if (j == 3) { f0 = eb[9]/vmax;     f1 = eb[10]/vmax;    f2 = eb[11]/vmax; }
    else             { int k = j-4; f0 = eb[12+0*3+k]; f1 = eb[12+1*3+k]; f2 = eb[12+2*3+k]; }
    float r = bc[o] + wc[o*3+0]*f0 + wc[o*3+1]*f1 + wc[o*3+2]*f2;
    hcat[(size_t)n*HCATW + 7500 + o*7 + j] = fmaxf(r, 0.f);
}

// ---------------------------------------------------------------------------
// FC0+FC1 fused, 4 samples per block (512 threads), h staged in LDS.
// Wave owns a 4-wide o-tile: 16 accumulators => each h b128 feeds 16 FMAs.
// wl0 L3 traffic = 256 blocks x 3 MB = 783 MB (half of FCNS=2).
// ---------------------------------------------------------------------------
__global__ __launch_bounds__(512) void fc01_kernel(const float* __restrict__ hcat,
                                                   const float* __restrict__ wl0,
                                                   const float* __restrict__ bl0,
                                                   const float* __restrict__ wl1,
                                                   const float* __restrict__ bl1,
                                                   float* __restrict__ out)
{
    __shared__ float hl[FCNS * HCATW];     // 122,240 B
    __shared__ float hbuf[FCNS * HID];     //   1,600 B
    const int tid = threadIdx.x;
    const int n0 = blockIdx.x * FCNS;
    for (int i = tid; i < FCNS * (HCATW/4); i += 512) {
        int s  = i / (HCATW/4);
        int k4 = i - s * (HCATW/4);
        ((float4*)hl)[s * (HCATW/4) + k4] =
            *(const float4*)(hcat + (size_t)(n0 + s) * HCATW + k4 * 4);
    }
    __syncthreads();
    const int wv = tid >> 6;
    const int lane = tid & 63;
    for (int ot = wv; ot < HID / 4; ot += 8) {      // 25 o-tiles of 4
        float acc[4][FCNS];
#pragma unroll
        for (int oo = 0; oo < 4; ++oo)
#pragma unroll
            for (int s = 0; s < FCNS; ++s) acc[oo][s] = 0.f;
        for (int k = lane * 4; k < HCATW; k += 256) {
            float4 hv[FCNS];
#pragma unroll
            for (int s = 0; s < FCNS; ++s)
                hv[s] = *(const float4*)(hl + s * HCATW + k);
#pragma unroll
            for (int oo = 0; oo < 4; ++oo) {
                const float4 w4 = *(const float4*)(wl0 + (size_t)(ot*4+oo) * HCATW + k);
#pragma unroll
                for (int s = 0; s < FCNS; ++s) {
                    acc[oo][s] = fmaf(hv[s].x, w4.x, acc[oo][s]);
                    acc[oo][s] = fmaf(hv[s].y, w4.y, acc[oo][s]);
                    acc[oo][s] = fmaf(hv[s].z, w4.z, acc[oo][s]);
                    acc[oo][s] = fmaf(hv[s].w, w4.w, acc[oo][s]);
                }
            }
        }
#pragma unroll
        for (int off = 32; off > 0; off >>= 1)
#pragma unroll
            for (int oo = 0; oo < 4; ++oo)
#pragma unroll
                for (int s = 0; s < FCNS; ++s)
                    acc[oo][s] += __shfl_down(acc[oo][s], off, 64);
        if (lane == 0) {
#pragma unroll
            for (int oo = 0; oo < 4; ++oo) {
                const float b = bl0[ot*4+oo];
#pragma unroll
                for (int s = 0; s < FCNS; ++s)
                    hbuf[s * HID + ot*4+oo] = fmaxf(acc[oo][s] + b, 0.f);
            }
        }
    }
    __syncthreads();
    if (tid < 2 * FCNS) {
        const int s = tid >> 1, r = tid & 1;
        const float* w = wl1 + r * HID;
        float acc = bl1[r];
        for (int k = 0; k < HID; ++k) acc = fmaf(hbuf[s * HID + k], w[k], acc);
        out[r * NBATCH + n0 + s] = acc;
    }
}

// ---------------------------------------------------------------------------
// launch
// ---------------------------------------------------------------------------
extern "C" void kernel_launch(void* const* d_in, const int* in_sizes, int n_in,
                              void* d_out, int out_size, void* d_ws, size_t ws_size,
                              hipStream_t stream)
{
    const float* x   = (const float*)d_in[0];
    const float* w0  = (const float*)d_in[1];
    const float* b0  = (const float*)d_in[2];
    const float* w1  = (const float*)d_in[3];
    const float* b1  = (const float*)d_in[4];
    const float* w2  = (const float*)d_in[5];
    const float* b2  = (const float*)d_in[6];
    const float* w3  = (const float*)d_in[7];
    const float* b3  = (const float*)d_in[8];
    const float* wc  = (const float*)d_in[9];
    const float* bc  = (const float*)d_in[10];
    const float* wl0 = (const float*)d_in[11];
    const float* bl0 = (const float*)d_in[12];
    const float* wl1 = (const float*)d_in[13];
    const float* bl1 = (const float*)d_in[14];
    float* out = (float*)d_out;

    // workspace layout (floats)
    const size_t HCAT_N = (size_t)NBATCH * HCATW;        // 7,823,360
    const size_t EIG_N  = (size_t)NBATCH * 21;
    const size_t need_bytes = (HCAT_N + EIG_N + 4 + WREPSZ) * 4 + 16;
    if (ws_size < need_bytes) return;

    float* ws     = (float*)d_ws;
    float* hcat   = ws;
    float* eigbuf = hcat + HCAT_N;
    unsigned int* gmax = (unsigned int*)(eigbuf + EIG_N);
    float* wrep   = (float*)(gmax + 4);

    hipMemsetAsync(gmax, 0, 2 * sizeof(unsigned int), stream);

    repack_kernel<<<24, 256, 0, stream>>>(w0, b0, w1, b1, w2, b2, w3, b3, wrep);
    conv_chain_eo<<<NBATCH * NCHK, 512, 0, stream>>>(x, wrep, hcat);
    cov_eig_kernel<<<NBATCH, 256, 0, stream>>>(x, eigbuf, gmax);
    feats_kernel<<<NBATCH, 256, 0, stream>>>(eigbuf, gmax, wc, bc, hcat);
    fc01_kernel<<<NBATCH / FCNS, 512, 0, stream>>>(hcat, wl0, bl0, wl1, bl1, out);
}